// Round 7
// baseline (160.687 us; speedup 1.0000x reference)
//
#include <hip/hip_runtime.h>
#include <hip/hip_bf16.h>
#include <math.h>

#define NEGF (-1e30f)
#define LOG2E 1.4426950408889634f
#define LN2F  0.6931471805599453f
#define TSCALE 2.885390081777927f     // 2*log2(e), folded into f and g

typedef __attribute__((ext_vector_type(8))) short bf16x8;
typedef __attribute__((ext_vector_type(4))) float f32x4;

#define DROWS_PAD 480        // diagonals 0..459 used; padded for static prefetch
#define DPITCH 64
#define PF 16                // prefetch depth (rows)

__device__ __forceinline__ unsigned short f2bf(float x) {
    __hip_bfloat16 h = __float2bfloat16(x);
    return *reinterpret_cast<unsigned short*>(&h);
}

__device__ __forceinline__ float wave_shr1(float x) {
    int i = __builtin_bit_cast(int, x);
    int r = __builtin_amdgcn_update_dpp(0, i, 0x138, 0xf, 0xf, true); // wf_shr:1
    return __builtin_bit_cast(float, r);
}

// row_ror:n DPP (16-lane ring rotate) — VALU-speed cross-lane, no LDS pipe.
#define ROR16(x, n) __builtin_bit_cast(float, __builtin_amdgcn_update_dpp( \
    0, __builtin_bit_cast(int, (x)), 0x120 + (n), 0xf, 0xf, true))

__device__ __forceinline__ float rmax16(float x) {
    x = fmaxf(x, ROR16(x, 8)); x = fmaxf(x, ROR16(x, 4));
    x = fmaxf(x, ROR16(x, 2)); x = fmaxf(x, ROR16(x, 1));
    return x;
}
__device__ __forceinline__ float rsum16(float x) {
    x += ROR16(x, 8); x += ROR16(x, 4); x += ROR16(x, 2); x += ROR16(x, 1);
    return x;
}

// reciprocal via bit-hack + 1 Newton step: pure VALU (no trans pipe).
__device__ __forceinline__ float4 rcp4_nr(float4 d) {
    float4 y;
    y.x = __builtin_bit_cast(float, 0x7EF311C3 - __builtin_bit_cast(int, d.x));
    y.y = __builtin_bit_cast(float, 0x7EF311C3 - __builtin_bit_cast(int, d.y));
    y.z = __builtin_bit_cast(float, 0x7EF311C3 - __builtin_bit_cast(int, d.z));
    y.w = __builtin_bit_cast(float, 0x7EF311C3 - __builtin_bit_cast(int, d.w));
    float4 t;
    t.x = fmaf(-d.x, y.x, 2.f); t.y = fmaf(-d.y, y.y, 2.f);
    t.z = fmaf(-d.z, y.z, 2.f); t.w = fmaf(-d.w, y.w, 2.f);
    y.x *= t.x; y.y *= t.y; y.z *= t.z; y.w *= t.w;
    return y;
}

// ---------------------------------------------------------------------------
// Kernel 0 (pack): bf16 B-fragments for We/Wd/-2*Wp; csbp = (colsum(Wp)+bp)*log2e
// ---------------------------------------------------------------------------
__global__ __launch_bounds__(256) void k_pack(const float* __restrict__ We,
                                              const float* __restrict__ Wd,
                                              const float* __restrict__ Wp,
                                              const float* __restrict__ bp,
                                              unsigned short* __restrict__ WeFrag,
                                              unsigned short* __restrict__ WdFrag,
                                              unsigned short* __restrict__ BfragP,
                                              float* __restrict__ csbp) {
    int gid = blockIdx.x * 256 + threadIdx.x;
    if (gid < 32768) {   // We / Wd
        const float* W = (gid < 16384) ? We : Wd;
        unsigned short* F = (gid < 16384) ? WeFrag : WdFrag;
        int s = gid & 16383;
        int lane = s & 63;
        int c = (s >> 6) & 7;
        int nt = s >> 9;
        int n = nt * 16 + (lane & 15);
        int kbase = c * 32 + ((lane >> 4) & 3) * 8;
        unsigned short* dst = F + (size_t)s * 8;
#pragma unroll
        for (int j = 0; j < 8; ++j) dst[j] = f2bf(W[(size_t)(kbase + j) * 512 + n]);
    } else if (gid < 34816) {            // -2*Wp: 2048 entries
        int s = gid - 32768;
        int lane = s & 63;
        int half = (s >> 6) & 1;
        int c = s >> 7;
        int n = half * 16 + (lane & 15);
        int kbase = c * 32 + (lane >> 4) * 8;
        unsigned short* dst = BfragP + (size_t)s * 8;
#pragma unroll
        for (int j = 0; j < 8; ++j) {
            float v = (n < 28) ? (-2.f * Wp[(kbase + j) * 28 + n]) : 0.f;
            dst[j] = f2bf(v);
        }
    } else if (gid < 34848) {            // csbp: 32 entries, pre-scaled to log2
        int v = gid - 34816;
        float s = 0.f;
        if (v < 28) {
            for (int k = 0; k < 512; ++k) s += Wp[k * 28 + v];
            s = (s + bp[v]) * LOG2E;
        }
        csbp[v] = s;
    }
}

// ---------------------------------------------------------------------------
// Kernel 1 (MFMA projections): f = (enc@We)*TSCALE, g = (dec@Wd + bf)*TSCALE.
// ---------------------------------------------------------------------------
__global__ __launch_bounds__(256) void k_gemm(const float* __restrict__ enc,
                                              const float* __restrict__ dec,
                                              const float* __restrict__ bfv,
                                              const unsigned short* __restrict__ WeFrag,
                                              const unsigned short* __restrict__ WdFrag,
                                              float* __restrict__ f,
                                              float* __restrict__ g) {
    const int wid = blockIdx.x * 4 + threadIdx.y;
    const int lane = threadIdx.x;
    const int m16 = lane & 15;
    const int quad = lane >> 4;

    const float* A; const unsigned short* WF; float* Out; int M, rt, ct; bool isg;
    if (wid < 1600) { A = enc; WF = WeFrag; Out = f; M = 3200; rt = wid >> 3; ct = wid & 7; isg = false; }
    else { int w2 = wid - 1600; A = dec; WF = WdFrag; Out = g; M = 488; rt = w2 >> 3; ct = w2 & 7; isg = true; }

    const int row = rt * 16 + m16;
    const float* arow = A + (size_t)min(row, M - 1) * 256 + quad * 8;

    f32x4 acc[4];
#pragma unroll
    for (int i = 0; i < 4; ++i) acc[i] = (f32x4){0.f, 0.f, 0.f, 0.f};

#pragma unroll
    for (int c = 0; c < 8; ++c) {
        float4 a0 = *(const float4*)(arow + c * 32);
        float4 a1 = *(const float4*)(arow + c * 32 + 4);
        union { unsigned short s[8]; bf16x8 v; } Af;
        Af.s[0] = f2bf(a0.x); Af.s[1] = f2bf(a0.y);
        Af.s[2] = f2bf(a0.z); Af.s[3] = f2bf(a0.w);
        Af.s[4] = f2bf(a1.x); Af.s[5] = f2bf(a1.y);
        Af.s[6] = f2bf(a1.z); Af.s[7] = f2bf(a1.w);
#pragma unroll
        for (int i = 0; i < 4; ++i) {
            int nt = ct * 4 + i;
            bf16x8 Bv = *(const bf16x8*)(WF + (size_t)((nt * 8 + c) * 64 + lane) * 8);
            acc[i] = __builtin_amdgcn_mfma_f32_16x16x32_bf16(Af.v, Bv, acc[i], 0, 0, 0);
        }
    }

#pragma unroll
    for (int i = 0; i < 4; ++i) {
        int n = ct * 64 + i * 16 + m16;
        float bv = isg ? bfv[n] : 0.f;
#pragma unroll
        for (int r = 0; r < 4; ++r) {
            int ro = rt * 16 + quad * 4 + r;
            if (ro < M) Out[(size_t)ro * 512 + n] = (acc[i][r] + bv) * TSCALE;
        }
    }
}

// ---------------------------------------------------------------------------
// Kernel 2: per-cell blank/label log2-probs. Each wave handles 16 t-rows x 4 u.
// sigma = 1/(1+exp2(f+g)) -> MFMA vs B=-2*Wp; logits(log2) = acc*log2e + csbp.
// grid (25 t-tiles, 4 u-groups, 8 b), block (64,4).
// ---------------------------------------------------------------------------
__global__ __launch_bounds__(256) void k_cells(const float* __restrict__ f,
                                               const float* __restrict__ g,
                                               const unsigned short* __restrict__ Bfrag,
                                               const float* __restrict__ csbp,
                                               const int* __restrict__ targets,
                                               const int* __restrict__ ilen,
                                               const int* __restrict__ ulenp,
                                               float2* __restrict__ pairD) {
    const int b = blockIdx.z;
    const int tlen = ilen[b];
    const int t0 = blockIdx.x * 16;
    if (t0 >= tlen) return;                        // block-uniform exit
    if ((int)blockIdx.y * 16 > ulenp[b]) return;   // u > ulen never feeds answer
    const int wave = threadIdx.y;
    const int lane = threadIdx.x;
    const int tid = wave * 64 + lane;
    const int ubase = blockIdx.y * 16 + wave * 4;

    __shared__ float fs[16 * 516];                 // stride 516: 2-way alias (free)

    {   // stage f tile (16 rows x 512), coalesced float4, conflict-free writes
        const float4* src = (const float4*)(f + (size_t)(b * 400 + t0) * 512);
#pragma unroll
        for (int i = 0; i < 8; ++i) {
            int idx = tid + i * 256;
            int row = idx >> 7;
            int c4 = idx & 127;
            float4 v = src[idx];
            *(float4*)&fs[row * 516 + c4 * 4] = v;
        }
    }
    __syncthreads();

    const int quad = lane >> 4;
    const int m16 = lane & 15;
    const float* fsrow = fs + m16 * 516 + quad * 8;
    const float* gb0 = g + (size_t)b * 61 * 512 + quad * 8;
    const float* gu[4];
    int us[4];
#pragma unroll
    for (int uu = 0; uu < 4; ++uu) {
        us[uu] = min(ubase + uu, 60);
        gu[uu] = gb0 + (size_t)us[uu] * 512;
    }

    f32x4 acc[4][2];
#pragma unroll
    for (int uu = 0; uu < 4; ++uu) {
        acc[uu][0] = (f32x4){0.f, 0.f, 0.f, 0.f};
        acc[uu][1] = (f32x4){0.f, 0.f, 0.f, 0.f};
    }
    const float4 one4 = make_float4(1.f, 1.f, 1.f, 1.f);

#pragma unroll 2
    for (int c = 0; c < 16; ++c) {
        float4 fa = *(const float4*)(fsrow + c * 32);        // shared across 4 u
        float4 fb = *(const float4*)(fsrow + c * 32 + 4);
        bf16x8 B0 = *(const bf16x8*)(Bfrag + ((size_t)(c * 2 + 0) * 64 + lane) * 8);
        bf16x8 B1 = *(const bf16x8*)(Bfrag + ((size_t)(c * 2 + 1) * 64 + lane) * 8);
#pragma unroll
        for (int uu = 0; uu < 4; ++uu) {
            float4 ga = *(const float4*)(gu[uu] + c * 32);
            float4 gb = *(const float4*)(gu[uu] + c * 32 + 4);
            float4 s0 = fa + ga;                   // pre-scaled by 2*log2e
            float4 s1 = fb + gb;
            float4 e0, e1;
            e0.x = __builtin_amdgcn_exp2f(s0.x); e0.y = __builtin_amdgcn_exp2f(s0.y);
            e0.z = __builtin_amdgcn_exp2f(s0.z); e0.w = __builtin_amdgcn_exp2f(s0.w);
            e1.x = __builtin_amdgcn_exp2f(s1.x); e1.y = __builtin_amdgcn_exp2f(s1.y);
            e1.z = __builtin_amdgcn_exp2f(s1.z); e1.w = __builtin_amdgcn_exp2f(s1.w);
            float4 r0 = rcp4_nr(e0 + one4);        // sigma, no trans rcp
            float4 r1 = rcp4_nr(e1 + one4);
            union { unsigned short s[8]; bf16x8 v; } A;
            A.s[0] = f2bf(r0.x); A.s[1] = f2bf(r0.y);
            A.s[2] = f2bf(r0.z); A.s[3] = f2bf(r0.w);
            A.s[4] = f2bf(r1.x); A.s[5] = f2bf(r1.y);
            A.s[6] = f2bf(r1.z); A.s[7] = f2bf(r1.w);
            acc[uu][0] = __builtin_amdgcn_mfma_f32_16x16x32_bf16(A.v, B0, acc[uu][0], 0, 0, 0);
            acc[uu][1] = __builtin_amdgcn_mfma_f32_16x16x32_bf16(A.v, B1, acc[uu][1], 0, 0, 0);
        }
    }

    // epilogue (log2 domain): l2[v] = acc*log2e + csbp2[v]
    const float cs0 = csbp[m16];
    const int n1 = 16 + m16;
    const bool n1v = (n1 < 28);
    const float cs1 = csbp[n1 & 31];
    const int base = lane & 48;
    float2* Pd = pairD + (size_t)b * (DROWS_PAD * DPITCH);

#pragma unroll
    for (int uu = 0; uu < 4; ++uu) {
        const int u = us[uu];
        const int tv = targets[b * 60 + min(u, 59)];
#pragma unroll
        for (int r = 0; r < 4; ++r) {
            float l0 = fmaf(acc[uu][0][r], LOG2E, cs0);
            float l1 = n1v ? fmaf(acc[uu][1][r], LOG2E, cs1) : NEGF;
            float mx = rmax16(fmaxf(l0, l1));                      // DPP ring-max
            float s = __builtin_amdgcn_exp2f(l0 - mx) +
                      __builtin_amdgcn_exp2f(l1 - mx);
            s = rsum16(s);                                          // DPP ring-sum
            float lse = mx + __builtin_amdgcn_logf(s);              // v_log_f32 = log2
            float labsrc = (tv < 16) ? l0 : l1;
            float labv = __shfl(labsrc, base | (tv & 15), 64);
            float blankv = __shfl(l1, base | 11, 64);               // v=27
            if (m16 == 0 && ubase + uu <= 60) {
                int t = t0 + quad * 4 + r;
                if (t < tlen) {
                    float2 pr;
                    pr.x = blankv - lse;
                    pr.y = (u <= 59) ? (labv - lse) : NEGF;
                    Pd[(t + u) * DPITCH + u] = pr;
                }
            }
        }
    }
}

// ---------------------------------------------------------------------------
// Kernel 3: anti-diagonal alpha recursion (log2 domain), one wave per batch.
// Static pipeline, per-batch uniform trip count, DPP lane shift.
// ---------------------------------------------------------------------------
__global__ __launch_bounds__(64) void k_alpha(const float2* __restrict__ pairD,
                                              const int* __restrict__ ilen,
                                              const int* __restrict__ ulenp,
                                              float* __restrict__ out) {
    const int b = blockIdx.x;
    const int u = threadIdx.x;
    const float2* Pd = pairD + (size_t)b * (DROWS_PAD * DPITCH);
    const int tl = ilen[b];
    const int ul = ulenp[b];
    const int dstar = tl - 1 + ul;
    const int dmax = ((dstar + PF - 1) / PF) * PF;   // uniform; <= 464
    const bool uok = (u <= 60);
    const bool lok = (u >= 1 && u <= 60);

    float cur = (u == 0) ? 0.f : NEGF;
    float saved = NEGF;

    float2 pf[PF];
#pragma unroll
    for (int i = 0; i < PF; ++i) pf[i] = Pd[i * DPITCH + u];

    for (int d0 = 1; d0 <= dmax; d0 += PF) {
#pragma unroll
        for (int i = 0; i < PF; ++i) {
            const int d = d0 + i;
            float2 v = pf[i];
            pf[i] = Pd[(d + PF - 1) * DPITCH + u];   // unconditional prefetch (<480)
            int t = d - u;
            float bv = (t >= 1 && t <= 399 && uok) ? v.x : NEGF;
            float lvn = wave_shr1(v.y);
            float lv = (lok && t >= 0 && t <= 399) ? lvn : NEGF;
            float up = wave_shr1(cur);
            float a = cur + bv;
            float c2 = up + lv;
            float mx = fmaxf(a, c2), mn = fminf(a, c2);
            float nv = mx + __builtin_amdgcn_logf(1.f + __builtin_amdgcn_exp2f(mn - mx));
            bool valid = (t >= 0 && t <= 399 && uok);
            cur = valid ? nv : cur;
            saved = (d == dstar) ? cur : saved;
        }
    }
    if (u == ul) out[b] = -(saved + Pd[dstar * DPITCH + u].x) * LN2F;
}

// ---------------------------------------------------------------------------
extern "C" void kernel_launch(void* const* d_in, const int* in_sizes, int n_in,
                              void* d_out, int out_size, void* d_ws, size_t ws_size,
                              hipStream_t stream) {
    const float* enc = (const float*)d_in[0];
    const float* dec = (const float*)d_in[1];
    const float* We  = (const float*)d_in[2];
    const float* Wd  = (const float*)d_in[3];
    const float* bf  = (const float*)d_in[4];
    const float* Wp  = (const float*)d_in[5];
    const float* bp  = (const float*)d_in[6];
    const int* targets = (const int*)d_in[7];
    const int* ilen    = (const int*)d_in[8];
    const int* ulen    = (const int*)d_in[9];
    float* out = (float*)d_out;
    float* ws = (float*)d_ws;

    float* f     = ws;                                        // 1,638,400 f
    float* g     = ws + 1638400;                              //   249,856 f
    unsigned short* BfragP = (unsigned short*)(ws + 1888256); //  16,384 u16
    unsigned short* WeFrag = (unsigned short*)(ws + 1896448); // 131,072 u16
    unsigned short* WdFrag = (unsigned short*)(ws + 1961984); // 131,072 u16
    float* csbp  = ws + 2027520;                              //        32 f
    float2* pairD = (float2*)(ws + 2027552);                  // 8*480*64 float2

    k_pack<<<137, 256, 0, stream>>>(We, Wd, Wp, bp, WeFrag, WdFrag, BfragP, csbp);

    k_gemm<<<462, dim3(64, 4, 1), 0, stream>>>(enc, dec, bf, WeFrag, WdFrag, f, g);

    dim3 gridC(25, 4, 8);
    dim3 blockC(64, 4, 1);
    k_cells<<<gridC, blockC, 0, stream>>>(f, g, BfragP, csbp, targets, ilen, ulen, pairD);

    k_alpha<<<8, 64, 0, stream>>>(pairD, ilen, ulen, out);
}